// Round 1
// baseline (76.077 us; speedup 1.0000x reference)
//
#include <hip/hip_runtime.h>

#define BATCH     256
#define INPUT_DIM 4096
#define SOMA      2048
#define BRANCHES  16
#define NDEND     32768
#define SAMPLE    32

#define B_T     4      // batch rows per block (LDS-limited: 4*4096*4B = 64KB)
#define D_T     2048   // dendrites per block
#define THREADS 256

__global__ __launch_bounds__(THREADS)
void dendrite_kernel(const float* __restrict__ x,
                     const int*   __restrict__ didx,
                     const float* __restrict__ sw,
                     const float* __restrict__ sb,
                     const float* __restrict__ cw,
                     const float* __restrict__ somab,
                     float* __restrict__ soma_out,   // [BATCH][SOMA]
                     float* __restrict__ dend_out)   // [BATCH][NDEND]
{
    __shared__ float xs[B_T][INPUT_DIM];   // 64 KiB exactly

    const int t  = threadIdx.x;
    const int bt = blockIdx.x;   // batch tile  (fastest-varying -> same d-chunk dispatched together)
    const int dc = blockIdx.y;   // dendrite chunk
    const int b0 = bt * B_T;
    const int d0 = dc * D_T;

    // ---- stage x rows into LDS (coalesced float4) ----
    #pragma unroll
    for (int bb = 0; bb < B_T; ++bb) {
        const float4* src = (const float4*)(x + (size_t)(b0 + bb) * INPUT_DIM);
        float4* dst = (float4*)(xs[bb]);
        #pragma unroll
        for (int r = 0; r < INPUT_DIM / 4 / THREADS; ++r)   // 4 iterations
            dst[r * THREADS + t] = src[r * THREADS + t];
    }
    __syncthreads();

    // ---- each thread owns one dendrite per iteration ----
    for (int it = 0; it < D_T / THREADS; ++it) {            // 8 iterations
        const int d = d0 + it * THREADS + t;

        const int4*   ip = (const int4*)  (didx + (size_t)d * SAMPLE);
        const float4* wp = (const float4*)(sw   + (size_t)d * SAMPLE);

        float acc[B_T] = {0.f, 0.f, 0.f, 0.f};

        #pragma unroll
        for (int g = 0; g < SAMPLE / 4; ++g) {              // 8 groups of 4 samples
            const int4   iv = ip[g];
            const float4 wv = wp[g];
            const int   ii[4] = {iv.x, iv.y, iv.z, iv.w};
            const float ww[4] = {wv.x, wv.y, wv.z, wv.w};
            #pragma unroll
            for (int u = 0; u < 4; ++u) {
                #pragma unroll
                for (int bb = 0; bb < B_T; ++bb)
                    acc[bb] += xs[bb][ii[u]] * ww[u];
            }
        }

        const float bias = sb[d];
        const float cwv  = cw[d];          // cable_weights flat-indexed by dendrite
        float part[B_T];

        #pragma unroll
        for (int bb = 0; bb < B_T; ++bb) {
            float pre = acc[bb] + bias;
            float act = (pre >= 0.f) ? pre : 0.1f * pre;
            dend_out[(size_t)(b0 + bb) * NDEND + d] = act;   // coalesced across lanes
            part[bb] = act * cwv;
        }

        // ---- soma: reduce 16 branches (16 consecutive lanes) ----
        #pragma unroll
        for (int m = 1; m < BRANCHES; m <<= 1) {
            #pragma unroll
            for (int bb = 0; bb < B_T; ++bb)
                part[bb] += __shfl_xor(part[bb], m);
        }

        if ((t & (BRANCHES - 1)) == 0) {
            const int n = d >> 4;
            const float sbi = somab[n];
            #pragma unroll
            for (int bb = 0; bb < B_T; ++bb) {
                float pre = part[bb] + sbi;
                soma_out[(size_t)(b0 + bb) * SOMA + n] = (pre >= 0.f) ? pre : 0.1f * pre;
            }
        }
    }
}

extern "C" void kernel_launch(void* const* d_in, const int* in_sizes, int n_in,
                              void* d_out, int out_size, void* d_ws, size_t ws_size,
                              hipStream_t stream) {
    const float* x     = (const float*)d_in[0];
    const int*   didx  = (const int*)  d_in[1];
    const float* sw    = (const float*)d_in[2];
    const float* sb    = (const float*)d_in[3];
    const float* cw    = (const float*)d_in[4];
    const float* somab = (const float*)d_in[5];

    float* soma_out = (float*)d_out;                     // [256][2048]
    float* dend_out = soma_out + (size_t)BATCH * SOMA;   // [256][32768]

    dim3 grid(BATCH / B_T, NDEND / D_T);                 // (64, 16)
    dendrite_kernel<<<grid, THREADS, 0, stream>>>(x, didx, sw, sb, cw, somab,
                                                  soma_out, dend_out);
}

// Round 2
// 73.169 us; speedup vs baseline: 1.0397x; 1.0397x over previous
//
#include <hip/hip_runtime.h>

#define BATCH     256
#define INPUT_DIM 4096
#define SOMA      2048
#define BRANCHES  16
#define NDEND     32768
#define SAMPLE    32

#define B_T     4      // batch rows per block
#define D_T     2048   // dendrites per block
#define THREADS 512

__global__ __launch_bounds__(THREADS, 4)   // 4 waves/SIMD min -> VGPR <= 128
void dendrite_kernel(const float* __restrict__ x,
                     const int*   __restrict__ didx,
                     const float* __restrict__ sw,
                     const float* __restrict__ sb,
                     const float* __restrict__ cw,
                     const float* __restrict__ somab,
                     float* __restrict__ soma_out,   // [BATCH][SOMA]
                     float* __restrict__ dend_out)   // [BATCH][NDEND]
{
    // Transposed x tile: xs[i*4 + bb] = x[b0+bb][i].  64 KiB.
    // One ds_read_b128 at addr i*16 yields all 4 batch rows for sample i.
    __shared__ float xs[INPUT_DIM * B_T];

    const int t  = threadIdx.x;
    const int bt = blockIdx.x;   // batch tile
    const int dc = blockIdx.y;   // dendrite chunk
    const int b0 = bt * B_T;
    const int d0 = dc * D_T;

    // ---- stage x transposed: 4 coalesced scalar loads -> 1 b128 write ----
    // write bank-group = i % 8; lanes t -> t%8: perfectly even, conflict-free
    const float* xb = x + (size_t)b0 * INPUT_DIM;
    #pragma unroll
    for (int r = 0; r < INPUT_DIM / THREADS; ++r) {   // 8 iterations
        const int i = r * THREADS + t;
        float4 v;
        v.x = xb[i];
        v.y = xb[INPUT_DIM     + i];
        v.z = xb[2 * INPUT_DIM + i];
        v.w = xb[3 * INPUT_DIM + i];
        *(float4*)&xs[i * B_T] = v;
    }
    __syncthreads();

    // ---- each thread owns one dendrite per iteration ----
    #pragma unroll
    for (int it = 0; it < D_T / THREADS; ++it) {      // 4 iterations
        const int d = d0 + it * THREADS + t;

        const int4*   ip = (const int4*)  (didx + (size_t)d * SAMPLE);
        const float4* wp = (const float4*)(sw   + (size_t)d * SAMPLE);

        float4 acc = {0.f, 0.f, 0.f, 0.f};           // acc.{x,y,z,w} = batch rows 0..3

        #pragma unroll
        for (int g = 0; g < SAMPLE / 4; ++g) {        // 8 groups of 4 samples
            const int4   iv = ip[g];
            const float4 wv = wp[g];
            float4 xv;

            xv = *(const float4*)&xs[iv.x * B_T];
            acc.x += xv.x * wv.x; acc.y += xv.y * wv.x;
            acc.z += xv.z * wv.x; acc.w += xv.w * wv.x;

            xv = *(const float4*)&xs[iv.y * B_T];
            acc.x += xv.x * wv.y; acc.y += xv.y * wv.y;
            acc.z += xv.z * wv.y; acc.w += xv.w * wv.y;

            xv = *(const float4*)&xs[iv.z * B_T];
            acc.x += xv.x * wv.z; acc.y += xv.y * wv.z;
            acc.z += xv.z * wv.z; acc.w += xv.w * wv.z;

            xv = *(const float4*)&xs[iv.w * B_T];
            acc.x += xv.x * wv.w; acc.y += xv.y * wv.w;
            acc.z += xv.z * wv.w; acc.w += xv.w * wv.w;
        }

        const float bias = sb[d];
        const float cwv  = cw[d];
        float part[B_T];
        float a[B_T] = {acc.x, acc.y, acc.z, acc.w};

        #pragma unroll
        for (int bb = 0; bb < B_T; ++bb) {
            float pre = a[bb] + bias;
            float act = (pre >= 0.f) ? pre : 0.1f * pre;
            dend_out[(size_t)(b0 + bb) * NDEND + d] = act;   // coalesced across lanes
            part[bb] = act * cwv;
        }

        // ---- soma: reduce 16 branches (16 consecutive lanes, within wave) ----
        #pragma unroll
        for (int m = 1; m < BRANCHES; m <<= 1) {
            #pragma unroll
            for (int bb = 0; bb < B_T; ++bb)
                part[bb] += __shfl_xor(part[bb], m);
        }

        if ((t & (BRANCHES - 1)) == 0) {
            const int n = d >> 4;
            const float sbi = somab[n];
            #pragma unroll
            for (int bb = 0; bb < B_T; ++bb) {
                float pre = part[bb] + sbi;
                soma_out[(size_t)(b0 + bb) * SOMA + n] = (pre >= 0.f) ? pre : 0.1f * pre;
            }
        }
    }
}

extern "C" void kernel_launch(void* const* d_in, const int* in_sizes, int n_in,
                              void* d_out, int out_size, void* d_ws, size_t ws_size,
                              hipStream_t stream) {
    const float* x     = (const float*)d_in[0];
    const int*   didx  = (const int*)  d_in[1];
    const float* sw    = (const float*)d_in[2];
    const float* sb    = (const float*)d_in[3];
    const float* cw    = (const float*)d_in[4];
    const float* somab = (const float*)d_in[5];

    float* soma_out = (float*)d_out;                     // [256][2048]
    float* dend_out = soma_out + (size_t)BATCH * SOMA;   // [256][32768]

    dim3 grid(BATCH / B_T, NDEND / D_T);                 // (64, 16)
    dendrite_kernel<<<grid, THREADS, 0, stream>>>(x, didx, sw, sb, cw, somab,
                                                  soma_out, dend_out);
}